// Round 10
// baseline (56.266 us; speedup 1.0000x reference)
//
#include <hip/hip_runtime.h>
#include <cmath>

#define HH 512
#define WW 512
#define TW 64      // tile width (output cols per block)
#define TH 32      // tile height (output rows per block)
#define SW 68      // column stride (floats), 272B, 16B-aligned
#define HB_R 40    // hblur rows  = TH + 2*4
#define BL_R 36    // blurred rows = TH + 2*2
#define MG_R 34    // mag rows     = TH + 2*1
#define NT 256

#define NG_A (HB_R * 17)   // 680 float4-groups per image
#define NG_B (BL_R * 17)   // 612
#define NG_C (MG_R * 17)   // 578

struct Blur5 { float w[5]; };

// packed (dr+1),(dc+1) 2-bit LUTs for the 8 NMS directions
// OFFS = {(0,1),(-1,1),(-1,0),(-1,-1),(0,-1),(1,-1),(1,0),(1,1)}
#define DR_PACK 43265u
#define DC_PACK 36890u

__device__ __forceinline__ float4 ld4(const float* p) {
  return *reinterpret_cast<const float4*>(p);
}
__device__ __forceinline__ void st4(float* p, float4 v) {
  *reinterpret_cast<float4*>(p) = v;
}

// rc = jnp.round((degrees(atan2(gy,gx)) + 180)/45) in [0,8], via comparisons.
// Validated vs reference R1-R8 (absmax 0.0).
__device__ __forceinline__ int orient_bin(float gx, float gy) {
  const float T1 = 0.41421356237309503f;  // tan(22.5)
  const float T2 = 2.41421356237309503f;  // tan(67.5)
  float a = fabsf(gy), b = fabsf(gx);
  int sx = (int)(__float_as_uint(gx) >> 31);
  int sy = (int)(__float_as_uint(gy) >> 31);
  int rc;
  if (a <= T1 * b)      rc = sx ? (8 - 8 * sy) : 4;
  else if (a >= T2 * b) rc = 6 - 4 * sy;
  else                  rc = sx ? (7 - 6 * sy) : (5 - 2 * sy);
  return rc;
}

// One region [2][40][68] holds hb, then bl (in-place), then mag (in-place).
// Phase C keeps center-mag (float4) and orientation bins (packed u32) in the
// producing thread's registers; phase D reuses them, reading only the two
// direction-dependent neighbors from LDS.
__global__ void __launch_bounds__(NT)
canny_loss_kernel(const float* __restrict__ X, const float* __restrict__ Y,
                  float* __restrict__ out, Blur5 kb)
{
  __shared__ float reg[2 * HB_R * SW];          // 21760 B
  __shared__ float red[NT / 64];
  float* rX = reg;
  float* rY = reg + HB_R * SW;

  // grid: 2048 blocks = 16 batch x 16 row-tiles x 8 col-tiles
  const int idx = blockIdx.x;
  const int b  = idx >> 7;
  const int tr = (idx >> 3) & 15;
  const int tc = idx & 7;
  const int base_r = tr * TH;
  const int base_c = tc * TW;
  const float* xb = X + (size_t)b * HH * WW;
  const float* yb = Y + (size_t)b * HH * WW;

  const int tid = threadIdx.x;
  const float k0 = kb.w[0], k1 = kb.w[1], k2 = kb.w[2], k3 = kb.w[3], k4 = kb.w[4];

  // ---- A: fused stage+hblur, both images -> reg as hb[40][68] ----
  #pragma unroll
  for (int it = 0; it < 3; ++it) {
    int g = tid + it * NT;
    if (g < NG_A) {
      int hr = (int)((unsigned)g / 17u), k = g - hr * 17;
      int gr = base_r + hr - 4;
      int gcb = base_c + k * 4 - 4;
      bool rok = (unsigned)gr < HH;
      bool ok0 = rok && (unsigned)gcb < WW;
      bool ok1 = rok && (unsigned)(gcb + 4) < WW;
      const float* px = xb + gr * WW + gcb;
      const float* py = yb + gr * WW + gcb;
      float4 xa = {0,0,0,0}, xc = {0,0,0,0}, ya = {0,0,0,0}, yc = {0,0,0,0};
      if (ok0) { xa = ld4(px); ya = ld4(py); }
      if (ok1) { xc = ld4(px + 4); yc = ld4(py + 4); }
      float4 ox, oy;
      ox.x = k0*xa.x + k1*xa.y + k2*xa.z + k3*xa.w + k4*xc.x;
      ox.y = k0*xa.y + k1*xa.z + k2*xa.w + k3*xc.x + k4*xc.y;
      ox.z = k0*xa.z + k1*xa.w + k2*xc.x + k3*xc.y + k4*xc.z;
      ox.w = k0*xa.w + k1*xc.x + k2*xc.y + k3*xc.z + k4*xc.w;
      oy.x = k0*ya.x + k1*ya.y + k2*ya.z + k3*ya.w + k4*yc.x;
      oy.y = k0*ya.y + k1*ya.z + k2*ya.w + k3*yc.x + k4*yc.y;
      oy.z = k0*ya.z + k1*ya.w + k2*yc.x + k3*yc.y + k4*yc.z;
      oy.w = k0*ya.w + k1*yc.x + k2*yc.y + k3*yc.z + k4*yc.w;
      st4(&rX[hr * SW + k * 4], ox);
      st4(&rY[hr * SW + k * 4], oy);
    }
  }
  __syncthreads();

  // ---- B compute: vertical blur -> registers; zero outside image ----
  float4 bx[3], by[3];
  #pragma unroll
  for (int it = 0; it < 3; ++it) {
    int g = tid + it * NT;
    if (g < NG_B) {
      int br = (int)((unsigned)g / 17u), k = g - br * 17, c4 = k * 4;
      bool rok = (unsigned)(base_r + br - 2) < HH;
      int gcb = base_c + c4 - 2;
      bool c0 = rok && (unsigned)(gcb + 0) < WW;
      bool c1 = rok && (unsigned)(gcb + 1) < WW;
      bool c2 = rok && (unsigned)(gcb + 2) < WW;
      bool c3 = rok && (unsigned)(gcb + 3) < WW;
      {
        const float* p = &rX[br * SW + c4];
        float4 v0 = ld4(p), v1 = ld4(p + SW), v2 = ld4(p + 2*SW),
               v3 = ld4(p + 3*SW), v4 = ld4(p + 4*SW);
        float4 o;
        o.x = c0 ? (k0*v0.x + k1*v1.x + k2*v2.x + k3*v3.x + k4*v4.x) : 0.f;
        o.y = c1 ? (k0*v0.y + k1*v1.y + k2*v2.y + k3*v3.y + k4*v4.y) : 0.f;
        o.z = c2 ? (k0*v0.z + k1*v1.z + k2*v2.z + k3*v3.z + k4*v4.z) : 0.f;
        o.w = c3 ? (k0*v0.w + k1*v1.w + k2*v2.w + k3*v3.w + k4*v4.w) : 0.f;
        bx[it] = o;
      }
      {
        const float* p = &rY[br * SW + c4];
        float4 v0 = ld4(p), v1 = ld4(p + SW), v2 = ld4(p + 2*SW),
               v3 = ld4(p + 3*SW), v4 = ld4(p + 4*SW);
        float4 o;
        o.x = c0 ? (k0*v0.x + k1*v1.x + k2*v2.x + k3*v3.x + k4*v4.x) : 0.f;
        o.y = c1 ? (k0*v0.y + k1*v1.y + k2*v2.y + k3*v3.y + k4*v4.y) : 0.f;
        o.z = c2 ? (k0*v0.z + k1*v1.z + k2*v2.z + k3*v3.z + k4*v4.z) : 0.f;
        o.w = c3 ? (k0*v0.w + k1*v1.w + k2*v2.w + k3*v3.w + k4*v4.w) : 0.f;
        by[it] = o;
      }
    }
  }
  __syncthreads();
  // ---- B write: bl overwrites hb rows 0..35 ----
  #pragma unroll
  for (int it = 0; it < 3; ++it) {
    int g = tid + it * NT;
    if (g < NG_B) {
      int br = (int)((unsigned)g / 17u), k = g - br * 17, c4 = k * 4;
      st4(&rX[br * SW + c4], bx[it]);
      st4(&rY[br * SW + c4], by[it]);
    }
  }
  __syncthreads();

  // ---- C compute: sobel mag -> regs (mx/my); orientation -> packed regs ----
  float4 mx[3], my[3];
  unsigned rcpx[3], rcpy[3];
  #pragma unroll
  for (int it = 0; it < 3; ++it) {
    int g = tid + it * NT;
    if (g < NG_C) {
      int mr = (int)((unsigned)g / 17u), k = g - mr * 17, c4 = k * 4;
      bool rok = (unsigned)(base_r + mr - 1) < HH;
      int gcb = base_c + c4 - 1;
      {
        const float* p = &rX[mr * SW + c4];
        float4 a0 = ld4(p),          b0 = ld4(p + 4);
        float4 a1 = ld4(p + SW),     b1 = ld4(p + SW + 4);
        float4 a2 = ld4(p + 2*SW),   b2 = ld4(p + 2*SW + 4);
        float e0[6] = {a0.x,a0.y,a0.z,a0.w,b0.x,b0.y};
        float e1[6] = {a1.x,a1.y,a1.z,a1.w,b1.x,b1.y};
        float e2[6] = {a2.x,a2.y,a2.z,a2.w,b2.x,b2.y};
        float4 o; float* po = &o.x;
        unsigned pk = 0;
        #pragma unroll
        for (int j = 0; j < 4; ++j) {
          float gx = (e0[j+2]-e0[j]) + 2.f*(e1[j+2]-e1[j]) + (e2[j+2]-e2[j]);
          float gy = (e2[j]-e0[j]) + 2.f*(e2[j+1]-e0[j+1]) + (e2[j+2]-e0[j+2]);
          pk |= (unsigned)orient_bin(gx, gy) << (8 * j);
          float m = sqrtf(gx*gx + gy*gy + 1e-12f);
          po[j] = (rok && (unsigned)(gcb + j) < WW) ? m : 0.f;
        }
        mx[it] = o; rcpx[it] = pk;
      }
      {
        const float* p = &rY[mr * SW + c4];
        float4 a0 = ld4(p),          b0 = ld4(p + 4);
        float4 a1 = ld4(p + SW),     b1 = ld4(p + SW + 4);
        float4 a2 = ld4(p + 2*SW),   b2 = ld4(p + 2*SW + 4);
        float e0[6] = {a0.x,a0.y,a0.z,a0.w,b0.x,b0.y};
        float e1[6] = {a1.x,a1.y,a1.z,a1.w,b1.x,b1.y};
        float e2[6] = {a2.x,a2.y,a2.z,a2.w,b2.x,b2.y};
        float4 o; float* po = &o.x;
        unsigned pk = 0;
        #pragma unroll
        for (int j = 0; j < 4; ++j) {
          float gx = (e0[j+2]-e0[j]) + 2.f*(e1[j+2]-e1[j]) + (e2[j+2]-e2[j]);
          float gy = (e2[j]-e0[j]) + 2.f*(e2[j+1]-e0[j+1]) + (e2[j+2]-e0[j+2]);
          pk |= (unsigned)orient_bin(gx, gy) << (8 * j);
          float m = sqrtf(gx*gx + gy*gy + 1e-12f);
          po[j] = (rok && (unsigned)(gcb + j) < WW) ? m : 0.f;
        }
        my[it] = o; rcpy[it] = pk;
      }
    }
  }
  __syncthreads();
  // ---- C write: mag overwrites bl rows 0..33 ----
  #pragma unroll
  for (int it = 0; it < 3; ++it) {
    int g = tid + it * NT;
    if (g < NG_C) {
      int mr = (int)((unsigned)g / 17u), k = g - mr * 17, c4 = k * 4;
      st4(&rX[mr * SW + c4], mx[it]);
      st4(&rY[mr * SW + c4], my[it]);
    }
  }
  __syncthreads();

  // ---- D: NMS + loss; center mag + rc from registers, neighbors from LDS ----
  // Thread handles centers (bi=mr-1, bj=c4-1+j) of its own C-groups.
  float s = 0.f; int so = 0;
  const float* pm[2] = {mx ? rX : rX, rY};  // (kept simple below)
  (void)pm;
  #pragma unroll
  for (int it = 0; it < 3; ++it) {
    int g = tid + it * NT;
    if (g < NG_C) {
      int mr = (int)((unsigned)g / 17u), k = g - mr * 17, c4 = k * 4;
      bool rowv = (unsigned)(mr - 1) < (unsigned)TH;   // bi in [0,32)
      const float* mcx = &mx[it].x;
      const float* mcy = &my[it].x;
      #pragma unroll
      for (int j = 0; j < 4; ++j) {
        int bj = c4 - 1 + j;
        bool valid = rowv && ((unsigned)bj < (unsigned)TW);
        int ci = mr * SW + c4 + j;     // mag coords of center
        // X
        int rcx = (int)((rcpx[it] >> (8 * j)) & 255u);
        int ip = rcx & 7;
        int dr = (int)((DR_PACK >> (2 * ip)) & 3u) - 1;
        int dc = (int)((DC_PACK >> (2 * ip)) & 3u) - 1;
        int off = dr * SW + dc;
        float mcv = mcx[j];
        float n1 = rX[ci + off];
        float n2 = rX[ci - off];
        float thx = (fminf(mcv - n1, mcv - n2) > 0.f) ? mcv : 0.f;
        // Y
        int rcy = (int)((rcpy[it] >> (8 * j)) & 255u);
        ip = rcy & 7;
        dr = (int)((DR_PACK >> (2 * ip)) & 3u) - 1;
        dc = (int)((DC_PACK >> (2 * ip)) & 3u) - 1;
        off = dr * SW + dc;
        float mcw = mcy[j];
        float m1 = rY[ci + off];
        float m2 = rY[ci - off];
        float thy = (fminf(mcw - m1, mcw - m2) > 0.f) ? mcw : 0.f;
        // loss (masked)
        s += valid ? fabsf(thx - thy) : 0.f;
        so += valid ? abs(rcx - rcy) : 0;
      }
    }
  }
  s += 45.f * (float)so;

  // wave reduce, cross-wave via LDS, one atomic per block
  #pragma unroll
  for (int off = 32; off >= 1; off >>= 1) s += __shfl_down(s, off, 64);
  const int lane = tid & 63, wv = tid >> 6;
  if (lane == 0) red[wv] = s;
  __syncthreads();
  if (tid == 0) {
    float t = red[0] + red[1] + red[2] + red[3];
    atomicAdd(out, t * (1.0f / ((float)HH * (float)WW)));
  }
}

extern "C" void kernel_launch(void* const* d_in, const int* in_sizes, int n_in,
                              void* d_out, int out_size, void* d_ws, size_t ws_size,
                              hipStream_t stream)
{
  const float* X = (const float*)d_in[0];
  const float* Y = (const float*)d_in[1];
  float* out = (float*)d_out;

  hipMemsetAsync(out, 0, (size_t)out_size * sizeof(float), stream);

  // Gaussian 1D weights in double, cast to f32 (matches reference f64->f32 path)
  Blur5 kb;
  {
    double g[5], ssum = 0.0;
    for (int i = 0; i < 5; ++i) { double d = i - 2; g[i] = std::exp(-(d * d) / 2.0); ssum += g[i]; }
    for (int i = 0; i < 5; ++i) kb.w[i] = (float)(g[i] / ssum);
  }

  canny_loss_kernel<<<2048, NT, 0, stream>>>(X, Y, out, kb);
}

// Round 11
// 41.728 us; speedup vs baseline: 1.3484x; 1.3484x over previous
//
#include <hip/hip_runtime.h>
#include <cmath>

#define HH 512
#define WW 512
#define TW 64      // tile width (output cols per block)
#define TH 64      // tile height (output rows per block)
#define SW 68      // column stride (floats), 272B, 16B-aligned
#define HB_R 72    // hblur rows  = TH + 2*4
#define BL_R 68    // blurred rows = TH + 2*2
#define MG_R 66    // mag rows     = TH + 2*1
#define NT 256
#define NIT 5      // ceil(HB_R*17 / NT)

#define NG_A (HB_R * 17)   // 1224 float4-groups per image
#define NG_B (BL_R * 17)   // 1156
#define NG_C (MG_R * 17)   // 1122

struct Blur5 { float w[5]; };

// packed (dr+1),(dc+1) 2-bit LUTs for the 8 NMS directions
// OFFS = {(0,1),(-1,1),(-1,0),(-1,-1),(0,-1),(1,-1),(1,0),(1,1)}
#define DR_PACK 43265u
#define DC_PACK 36890u

__device__ __forceinline__ float4 ld4(const float* p) {
  return *reinterpret_cast<const float4*>(p);
}
__device__ __forceinline__ void st4(float* p, float4 v) {
  *reinterpret_cast<float4*>(p) = v;
}

// rc = jnp.round((degrees(atan2(gy,gx)) + 180)/45) in [0,8], via comparisons.
// Validated vs reference R1-R9 (absmax 0.0).
__device__ __forceinline__ int orient_bin(float gx, float gy) {
  const float T1 = 0.41421356237309503f;  // tan(22.5)
  const float T2 = 2.41421356237309503f;  // tan(67.5)
  float a = fabsf(gy), b = fabsf(gx);
  int sx = (int)(__float_as_uint(gx) >> 31);
  int sy = (int)(__float_as_uint(gy) >> 31);
  int rc;
  if (a <= T1 * b)      rc = sx ? (8 - 8 * sy) : 4;
  else if (a >= T2 * b) rc = 6 - 4 * sy;
  else                  rc = sx ? (7 - 6 * sy) : (5 - 2 * sy);
  return rc;
}

// One region [2][72][68] holds hb, then bl (in-place), then mag (in-place).
// Phase C keeps center-mag (float4) and orientation bins (packed u32) in the
// producing thread's registers; phase D reuses them, reading only the two
// direction-dependent neighbors from LDS.
__global__ void __launch_bounds__(NT)
canny_loss_kernel(const float* __restrict__ X, const float* __restrict__ Y,
                  float* __restrict__ out, Blur5 kb)
{
  __shared__ float reg[2 * HB_R * SW];          // 39168 B
  __shared__ float red[NT / 64];
  float* rX = reg;
  float* rY = reg + HB_R * SW;

  // grid: 1024 blocks = 16 batch x 8 row-tiles x 8 col-tiles (= 4 blocks/CU)
  const int idx = blockIdx.x;
  const int b  = idx >> 6;
  const int tr = (idx >> 3) & 7;
  const int tc = idx & 7;
  const int base_r = tr * TH;
  const int base_c = tc * TW;
  const float* xb = X + (size_t)b * HH * WW;
  const float* yb = Y + (size_t)b * HH * WW;

  const int tid = threadIdx.x;
  const float k0 = kb.w[0], k1 = kb.w[1], k2 = kb.w[2], k3 = kb.w[3], k4 = kb.w[4];

  // ---- A: fused stage+hblur, both images -> reg as hb[72][68] ----
  #pragma unroll
  for (int it = 0; it < NIT; ++it) {
    int g = tid + it * NT;
    if (g < NG_A) {
      int hr = (int)((unsigned)g / 17u), k = g - hr * 17;
      int gr = base_r + hr - 4;
      int gcb = base_c + k * 4 - 4;
      bool rok = (unsigned)gr < HH;
      bool ok0 = rok && (unsigned)gcb < WW;
      bool ok1 = rok && (unsigned)(gcb + 4) < WW;
      const float* px = xb + gr * WW + gcb;
      const float* py = yb + gr * WW + gcb;
      float4 xa = {0,0,0,0}, xc = {0,0,0,0}, ya = {0,0,0,0}, yc = {0,0,0,0};
      if (ok0) { xa = ld4(px); ya = ld4(py); }
      if (ok1) { xc = ld4(px + 4); yc = ld4(py + 4); }
      float4 ox, oy;
      ox.x = k0*xa.x + k1*xa.y + k2*xa.z + k3*xa.w + k4*xc.x;
      ox.y = k0*xa.y + k1*xa.z + k2*xa.w + k3*xc.x + k4*xc.y;
      ox.z = k0*xa.z + k1*xa.w + k2*xc.x + k3*xc.y + k4*xc.z;
      ox.w = k0*xa.w + k1*xc.x + k2*xc.y + k3*xc.z + k4*xc.w;
      oy.x = k0*ya.x + k1*ya.y + k2*ya.z + k3*ya.w + k4*yc.x;
      oy.y = k0*ya.y + k1*ya.z + k2*ya.w + k3*yc.x + k4*yc.y;
      oy.z = k0*ya.z + k1*ya.w + k2*yc.x + k3*yc.y + k4*yc.z;
      oy.w = k0*ya.w + k1*yc.x + k2*yc.y + k3*yc.z + k4*yc.w;
      st4(&rX[hr * SW + k * 4], ox);
      st4(&rY[hr * SW + k * 4], oy);
    }
  }
  __syncthreads();

  // ---- B compute: vertical blur -> registers; zero outside image ----
  float4 bx[NIT], by[NIT];
  #pragma unroll
  for (int it = 0; it < NIT; ++it) {
    int g = tid + it * NT;
    if (g < NG_B) {
      int br = (int)((unsigned)g / 17u), k = g - br * 17, c4 = k * 4;
      bool rok = (unsigned)(base_r + br - 2) < HH;
      int gcb = base_c + c4 - 2;
      bool c0 = rok && (unsigned)(gcb + 0) < WW;
      bool c1 = rok && (unsigned)(gcb + 1) < WW;
      bool c2 = rok && (unsigned)(gcb + 2) < WW;
      bool c3 = rok && (unsigned)(gcb + 3) < WW;
      {
        const float* p = &rX[br * SW + c4];
        float4 v0 = ld4(p), v1 = ld4(p + SW), v2 = ld4(p + 2*SW),
               v3 = ld4(p + 3*SW), v4 = ld4(p + 4*SW);
        float4 o;
        o.x = c0 ? (k0*v0.x + k1*v1.x + k2*v2.x + k3*v3.x + k4*v4.x) : 0.f;
        o.y = c1 ? (k0*v0.y + k1*v1.y + k2*v2.y + k3*v3.y + k4*v4.y) : 0.f;
        o.z = c2 ? (k0*v0.z + k1*v1.z + k2*v2.z + k3*v3.z + k4*v4.z) : 0.f;
        o.w = c3 ? (k0*v0.w + k1*v1.w + k2*v2.w + k3*v3.w + k4*v4.w) : 0.f;
        bx[it] = o;
      }
      {
        const float* p = &rY[br * SW + c4];
        float4 v0 = ld4(p), v1 = ld4(p + SW), v2 = ld4(p + 2*SW),
               v3 = ld4(p + 3*SW), v4 = ld4(p + 4*SW);
        float4 o;
        o.x = c0 ? (k0*v0.x + k1*v1.x + k2*v2.x + k3*v3.x + k4*v4.x) : 0.f;
        o.y = c1 ? (k0*v0.y + k1*v1.y + k2*v2.y + k3*v3.y + k4*v4.y) : 0.f;
        o.z = c2 ? (k0*v0.z + k1*v1.z + k2*v2.z + k3*v3.z + k4*v4.z) : 0.f;
        o.w = c3 ? (k0*v0.w + k1*v1.w + k2*v2.w + k3*v3.w + k4*v4.w) : 0.f;
        by[it] = o;
      }
    }
  }
  __syncthreads();
  // ---- B write: bl overwrites hb rows 0..67 ----
  #pragma unroll
  for (int it = 0; it < NIT; ++it) {
    int g = tid + it * NT;
    if (g < NG_B) {
      int br = (int)((unsigned)g / 17u), k = g - br * 17, c4 = k * 4;
      st4(&rX[br * SW + c4], bx[it]);
      st4(&rY[br * SW + c4], by[it]);
    }
  }
  __syncthreads();

  // ---- C compute: sobel mag -> regs (mx/my); orientation -> packed regs ----
  float4 mx[NIT], my[NIT];
  unsigned rcpx[NIT], rcpy[NIT];
  #pragma unroll
  for (int it = 0; it < NIT; ++it) {
    int g = tid + it * NT;
    if (g < NG_C) {
      int mr = (int)((unsigned)g / 17u), k = g - mr * 17, c4 = k * 4;
      bool rok = (unsigned)(base_r + mr - 1) < HH;
      int gcb = base_c + c4 - 1;
      {
        const float* p = &rX[mr * SW + c4];
        float4 a0 = ld4(p),          b0 = ld4(p + 4);
        float4 a1 = ld4(p + SW),     b1 = ld4(p + SW + 4);
        float4 a2 = ld4(p + 2*SW),   b2 = ld4(p + 2*SW + 4);
        float e0[6] = {a0.x,a0.y,a0.z,a0.w,b0.x,b0.y};
        float e1[6] = {a1.x,a1.y,a1.z,a1.w,b1.x,b1.y};
        float e2[6] = {a2.x,a2.y,a2.z,a2.w,b2.x,b2.y};
        float4 o; float* po = &o.x;
        unsigned pk = 0;
        #pragma unroll
        for (int j = 0; j < 4; ++j) {
          float gx = (e0[j+2]-e0[j]) + 2.f*(e1[j+2]-e1[j]) + (e2[j+2]-e2[j]);
          float gy = (e2[j]-e0[j]) + 2.f*(e2[j+1]-e0[j+1]) + (e2[j+2]-e0[j+2]);
          pk |= (unsigned)orient_bin(gx, gy) << (8 * j);
          float m = sqrtf(gx*gx + gy*gy + 1e-12f);
          po[j] = (rok && (unsigned)(gcb + j) < WW) ? m : 0.f;
        }
        mx[it] = o; rcpx[it] = pk;
      }
      {
        const float* p = &rY[mr * SW + c4];
        float4 a0 = ld4(p),          b0 = ld4(p + 4);
        float4 a1 = ld4(p + SW),     b1 = ld4(p + SW + 4);
        float4 a2 = ld4(p + 2*SW),   b2 = ld4(p + 2*SW + 4);
        float e0[6] = {a0.x,a0.y,a0.z,a0.w,b0.x,b0.y};
        float e1[6] = {a1.x,a1.y,a1.z,a1.w,b1.x,b1.y};
        float e2[6] = {a2.x,a2.y,a2.z,a2.w,b2.x,b2.y};
        float4 o; float* po = &o.x;
        unsigned pk = 0;
        #pragma unroll
        for (int j = 0; j < 4; ++j) {
          float gx = (e0[j+2]-e0[j]) + 2.f*(e1[j+2]-e1[j]) + (e2[j+2]-e2[j]);
          float gy = (e2[j]-e0[j]) + 2.f*(e2[j+1]-e0[j+1]) + (e2[j+2]-e0[j+2]);
          pk |= (unsigned)orient_bin(gx, gy) << (8 * j);
          float m = sqrtf(gx*gx + gy*gy + 1e-12f);
          po[j] = (rok && (unsigned)(gcb + j) < WW) ? m : 0.f;
        }
        my[it] = o; rcpy[it] = pk;
      }
    }
  }
  __syncthreads();
  // ---- C write: mag overwrites bl rows 0..65 ----
  #pragma unroll
  for (int it = 0; it < NIT; ++it) {
    int g = tid + it * NT;
    if (g < NG_C) {
      int mr = (int)((unsigned)g / 17u), k = g - mr * 17, c4 = k * 4;
      st4(&rX[mr * SW + c4], mx[it]);
      st4(&rY[mr * SW + c4], my[it]);
    }
  }
  __syncthreads();

  // ---- D: NMS + loss; center mag + rc from registers, neighbors from LDS ----
  float s = 0.f; int so = 0;
  #pragma unroll
  for (int it = 0; it < NIT; ++it) {
    int g = tid + it * NT;
    if (g < NG_C) {
      int mr = (int)((unsigned)g / 17u), k = g - mr * 17, c4 = k * 4;
      bool rowv = (unsigned)(mr - 1) < (unsigned)TH;   // bi in [0,64)
      const float* mcx = &mx[it].x;
      const float* mcy = &my[it].x;
      #pragma unroll
      for (int j = 0; j < 4; ++j) {
        int bj = c4 - 1 + j;
        bool valid = rowv && ((unsigned)bj < (unsigned)TW);
        int ci = mr * SW + c4 + j;     // mag coords of center
        // X
        int rcx = (int)((rcpx[it] >> (8 * j)) & 255u);
        int ip = rcx & 7;
        int dr = (int)((DR_PACK >> (2 * ip)) & 3u) - 1;
        int dc = (int)((DC_PACK >> (2 * ip)) & 3u) - 1;
        int off = dr * SW + dc;
        float mcv = mcx[j];
        float n1 = rX[ci + off];
        float n2 = rX[ci - off];
        float thx = (fminf(mcv - n1, mcv - n2) > 0.f) ? mcv : 0.f;
        // Y
        int rcy = (int)((rcpy[it] >> (8 * j)) & 255u);
        ip = rcy & 7;
        dr = (int)((DR_PACK >> (2 * ip)) & 3u) - 1;
        dc = (int)((DC_PACK >> (2 * ip)) & 3u) - 1;
        off = dr * SW + dc;
        float mcw = mcy[j];
        float m1 = rY[ci + off];
        float m2 = rY[ci - off];
        float thy = (fminf(mcw - m1, mcw - m2) > 0.f) ? mcw : 0.f;
        // loss (masked)
        s += valid ? fabsf(thx - thy) : 0.f;
        so += valid ? abs(rcx - rcy) : 0;
      }
    }
  }
  s += 45.f * (float)so;

  // wave reduce, cross-wave via LDS, one atomic per block
  #pragma unroll
  for (int off = 32; off >= 1; off >>= 1) s += __shfl_down(s, off, 64);
  const int lane = tid & 63, wv = tid >> 6;
  if (lane == 0) red[wv] = s;
  __syncthreads();
  if (tid == 0) {
    float t = red[0] + red[1] + red[2] + red[3];
    atomicAdd(out, t * (1.0f / ((float)HH * (float)WW)));
  }
}

extern "C" void kernel_launch(void* const* d_in, const int* in_sizes, int n_in,
                              void* d_out, int out_size, void* d_ws, size_t ws_size,
                              hipStream_t stream)
{
  const float* X = (const float*)d_in[0];
  const float* Y = (const float*)d_in[1];
  float* out = (float*)d_out;

  hipMemsetAsync(out, 0, (size_t)out_size * sizeof(float), stream);

  // Gaussian 1D weights in double, cast to f32 (matches reference f64->f32 path)
  Blur5 kb;
  {
    double g[5], ssum = 0.0;
    for (int i = 0; i < 5; ++i) { double d = i - 2; g[i] = std::exp(-(d * d) / 2.0); ssum += g[i]; }
    for (int i = 0; i < 5; ++i) kb.w[i] = (float)(g[i] / ssum);
  }

  canny_loss_kernel<<<1024, NT, 0, stream>>>(X, Y, out, kb);
}

// Round 12
// 40.175 us; speedup vs baseline: 1.4005x; 1.0387x over previous
//
#include <hip/hip_runtime.h>
#include <cmath>

#define HH 512
#define WW 512
#define TW 64      // tile width (output cols per block)
#define TH 64      // tile height (output rows per block)
#define SW 68      // column stride (floats), 272B, 16B-aligned
#define HB_R 72    // hblur rows  = TH + 2*4
#define BL_R 68    // blurred rows = TH + 2*2
#define MG_R 66    // mag rows     = TH + 2*1
#define NT 256
#define NIT 5      // ceil(HB_R*17 / NT)

#define NG_A (HB_R * 17)   // 1224 float4-groups per image
#define NG_B (BL_R * 17)   // 1156
#define NG_C (MG_R * 17)   // 1122

struct Blur5 { float w[5]; };

// packed (dr+1),(dc+1) 2-bit LUTs for the 8 NMS directions
// OFFS = {(0,1),(-1,1),(-1,0),(-1,-1),(0,-1),(1,-1),(1,0),(1,1)}
#define DR_PACK 43265u
#define DC_PACK 36890u

__device__ __forceinline__ float4 ld4(const float* p) {
  return *reinterpret_cast<const float4*>(p);
}
__device__ __forceinline__ void st4(float* p, float4 v) {
  *reinterpret_cast<float4*>(p) = v;
}

// rc = jnp.round((degrees(atan2(gy,gx)) + 180)/45) in [0,8], via comparisons.
// Validated vs reference R1-R10 (absmax 0.0).
__device__ __forceinline__ int orient_bin(float gx, float gy) {
  const float T1 = 0.41421356237309503f;  // tan(22.5)
  const float T2 = 2.41421356237309503f;  // tan(67.5)
  float a = fabsf(gy), b = fabsf(gx);
  int sx = (int)(__float_as_uint(gx) >> 31);
  int sy = (int)(__float_as_uint(gy) >> 31);
  int rc;
  if (a <= T1 * b)      rc = sx ? (8 - 8 * sy) : 4;
  else if (a >= T2 * b) rc = 6 - 4 * sy;
  else                  rc = sx ? (7 - 6 * sy) : (5 - 2 * sy);
  return rc;
}

// One region [2][72][68] holds hb, then bl (in-place), then mag (in-place).
// Phase C keeps center-mag (float4) and orientation bins (packed u32) in the
// producing thread's registers; phase D reuses them, reading only the two
// direction-dependent neighbors from LDS.
// INTERIOR: tile is >=4 px away from every image edge -> all bounds checks
// are compile-time true (dropped); phase A loads issue unconditionally.
template<bool INTERIOR>
__device__ __forceinline__ float canny_tile_loss(
    const float* __restrict__ xb, const float* __restrict__ yb,
    int base_r, int base_c, float* __restrict__ rX, float* __restrict__ rY,
    const Blur5& kb)
{
  const int tid = threadIdx.x;
  const float k0 = kb.w[0], k1 = kb.w[1], k2 = kb.w[2], k3 = kb.w[3], k4 = kb.w[4];

  // ---- A: fused stage+hblur, both images -> reg as hb[72][68] ----
  #pragma unroll
  for (int it = 0; it < NIT; ++it) {
    int g = tid + it * NT;
    if (g < NG_A) {
      int hr = (int)((unsigned)g / 17u), k = g - hr * 17;
      int gr = base_r + hr - 4;
      int gcb = base_c + k * 4 - 4;
      const float* px = xb + gr * WW + gcb;
      const float* py = yb + gr * WW + gcb;
      float4 xa = {0,0,0,0}, xc = {0,0,0,0}, ya = {0,0,0,0}, yc = {0,0,0,0};
      if (INTERIOR) {
        xa = ld4(px); ya = ld4(py);
        xc = ld4(px + 4); yc = ld4(py + 4);
      } else {
        bool rok = (unsigned)gr < HH;
        bool ok0 = rok && (unsigned)gcb < WW;
        bool ok1 = rok && (unsigned)(gcb + 4) < WW;
        if (ok0) { xa = ld4(px); ya = ld4(py); }
        if (ok1) { xc = ld4(px + 4); yc = ld4(py + 4); }
      }
      float4 ox, oy;
      ox.x = k0*xa.x + k1*xa.y + k2*xa.z + k3*xa.w + k4*xc.x;
      ox.y = k0*xa.y + k1*xa.z + k2*xa.w + k3*xc.x + k4*xc.y;
      ox.z = k0*xa.z + k1*xa.w + k2*xc.x + k3*xc.y + k4*xc.z;
      ox.w = k0*xa.w + k1*xc.x + k2*xc.y + k3*xc.z + k4*xc.w;
      oy.x = k0*ya.x + k1*ya.y + k2*ya.z + k3*ya.w + k4*yc.x;
      oy.y = k0*ya.y + k1*ya.z + k2*ya.w + k3*yc.x + k4*yc.y;
      oy.z = k0*ya.z + k1*ya.w + k2*yc.x + k3*yc.y + k4*yc.z;
      oy.w = k0*ya.w + k1*yc.x + k2*yc.y + k3*yc.z + k4*yc.w;
      st4(&rX[hr * SW + k * 4], ox);
      st4(&rY[hr * SW + k * 4], oy);
    }
  }
  __syncthreads();

  // ---- B compute: vertical blur -> registers; zero outside image ----
  float4 bx[NIT], by[NIT];
  #pragma unroll
  for (int it = 0; it < NIT; ++it) {
    int g = tid + it * NT;
    if (g < NG_B) {
      int br = (int)((unsigned)g / 17u), k = g - br * 17, c4 = k * 4;
      bool c0 = true, c1 = true, c2 = true, c3 = true;
      if (!INTERIOR) {
        bool rok = (unsigned)(base_r + br - 2) < HH;
        int gcb = base_c + c4 - 2;
        c0 = rok && (unsigned)(gcb + 0) < WW;
        c1 = rok && (unsigned)(gcb + 1) < WW;
        c2 = rok && (unsigned)(gcb + 2) < WW;
        c3 = rok && (unsigned)(gcb + 3) < WW;
      }
      {
        const float* p = &rX[br * SW + c4];
        float4 v0 = ld4(p), v1 = ld4(p + SW), v2 = ld4(p + 2*SW),
               v3 = ld4(p + 3*SW), v4 = ld4(p + 4*SW);
        float4 o;
        o.x = c0 ? (k0*v0.x + k1*v1.x + k2*v2.x + k3*v3.x + k4*v4.x) : 0.f;
        o.y = c1 ? (k0*v0.y + k1*v1.y + k2*v2.y + k3*v3.y + k4*v4.y) : 0.f;
        o.z = c2 ? (k0*v0.z + k1*v1.z + k2*v2.z + k3*v3.z + k4*v4.z) : 0.f;
        o.w = c3 ? (k0*v0.w + k1*v1.w + k2*v2.w + k3*v3.w + k4*v4.w) : 0.f;
        bx[it] = o;
      }
      {
        const float* p = &rY[br * SW + c4];
        float4 v0 = ld4(p), v1 = ld4(p + SW), v2 = ld4(p + 2*SW),
               v3 = ld4(p + 3*SW), v4 = ld4(p + 4*SW);
        float4 o;
        o.x = c0 ? (k0*v0.x + k1*v1.x + k2*v2.x + k3*v3.x + k4*v4.x) : 0.f;
        o.y = c1 ? (k0*v0.y + k1*v1.y + k2*v2.y + k3*v3.y + k4*v4.y) : 0.f;
        o.z = c2 ? (k0*v0.z + k1*v1.z + k2*v2.z + k3*v3.z + k4*v4.z) : 0.f;
        o.w = c3 ? (k0*v0.w + k1*v1.w + k2*v2.w + k3*v3.w + k4*v4.w) : 0.f;
        by[it] = o;
      }
    }
  }
  __syncthreads();
  // ---- B write: bl overwrites hb rows 0..67 ----
  #pragma unroll
  for (int it = 0; it < NIT; ++it) {
    int g = tid + it * NT;
    if (g < NG_B) {
      int br = (int)((unsigned)g / 17u), k = g - br * 17, c4 = k * 4;
      st4(&rX[br * SW + c4], bx[it]);
      st4(&rY[br * SW + c4], by[it]);
    }
  }
  __syncthreads();

  // ---- C compute: sobel mag -> regs (mx/my); orientation -> packed regs ----
  float4 mx[NIT], my[NIT];
  unsigned rcpx[NIT], rcpy[NIT];
  #pragma unroll
  for (int it = 0; it < NIT; ++it) {
    int g = tid + it * NT;
    if (g < NG_C) {
      int mr = (int)((unsigned)g / 17u), k = g - mr * 17, c4 = k * 4;
      bool rok = true;
      int gcb = base_c + c4 - 1;
      if (!INTERIOR) rok = (unsigned)(base_r + mr - 1) < HH;
      {
        const float* p = &rX[mr * SW + c4];
        float4 a0 = ld4(p),          b0 = ld4(p + 4);
        float4 a1 = ld4(p + SW),     b1 = ld4(p + SW + 4);
        float4 a2 = ld4(p + 2*SW),   b2 = ld4(p + 2*SW + 4);
        float e0[6] = {a0.x,a0.y,a0.z,a0.w,b0.x,b0.y};
        float e1[6] = {a1.x,a1.y,a1.z,a1.w,b1.x,b1.y};
        float e2[6] = {a2.x,a2.y,a2.z,a2.w,b2.x,b2.y};
        float4 o; float* po = &o.x;
        unsigned pk = 0;
        #pragma unroll
        for (int j = 0; j < 4; ++j) {
          float gx = (e0[j+2]-e0[j]) + 2.f*(e1[j+2]-e1[j]) + (e2[j+2]-e2[j]);
          float gy = (e2[j]-e0[j]) + 2.f*(e2[j+1]-e0[j+1]) + (e2[j+2]-e0[j+2]);
          pk |= (unsigned)orient_bin(gx, gy) << (8 * j);
          float m = sqrtf(gx*gx + gy*gy + 1e-12f);
          if (INTERIOR) po[j] = m;
          else po[j] = (rok && (unsigned)(gcb + j) < WW) ? m : 0.f;
        }
        mx[it] = o; rcpx[it] = pk;
      }
      {
        const float* p = &rY[mr * SW + c4];
        float4 a0 = ld4(p),          b0 = ld4(p + 4);
        float4 a1 = ld4(p + SW),     b1 = ld4(p + SW + 4);
        float4 a2 = ld4(p + 2*SW),   b2 = ld4(p + 2*SW + 4);
        float e0[6] = {a0.x,a0.y,a0.z,a0.w,b0.x,b0.y};
        float e1[6] = {a1.x,a1.y,a1.z,a1.w,b1.x,b1.y};
        float e2[6] = {a2.x,a2.y,a2.z,a2.w,b2.x,b2.y};
        float4 o; float* po = &o.x;
        unsigned pk = 0;
        #pragma unroll
        for (int j = 0; j < 4; ++j) {
          float gx = (e0[j+2]-e0[j]) + 2.f*(e1[j+2]-e1[j]) + (e2[j+2]-e2[j]);
          float gy = (e2[j]-e0[j]) + 2.f*(e2[j+1]-e0[j+1]) + (e2[j+2]-e0[j+2]);
          pk |= (unsigned)orient_bin(gx, gy) << (8 * j);
          float m = sqrtf(gx*gx + gy*gy + 1e-12f);
          if (INTERIOR) po[j] = m;
          else po[j] = (rok && (unsigned)(gcb + j) < WW) ? m : 0.f;
        }
        my[it] = o; rcpy[it] = pk;
      }
    }
  }
  __syncthreads();
  // ---- C write: mag overwrites bl rows 0..65 ----
  #pragma unroll
  for (int it = 0; it < NIT; ++it) {
    int g = tid + it * NT;
    if (g < NG_C) {
      int mr = (int)((unsigned)g / 17u), k = g - mr * 17, c4 = k * 4;
      st4(&rX[mr * SW + c4], mx[it]);
      st4(&rY[mr * SW + c4], my[it]);
    }
  }
  __syncthreads();

  // ---- D: NMS + loss; center mag + rc from registers, neighbors from LDS ----
  float s = 0.f; int so = 0;
  #pragma unroll
  for (int it = 0; it < NIT; ++it) {
    int g = tid + it * NT;
    if (g < NG_C) {
      int mr = (int)((unsigned)g / 17u), k = g - mr * 17, c4 = k * 4;
      bool rowv = (unsigned)(mr - 1) < (unsigned)TH;   // bi in [0,64)
      const float* mcx = &mx[it].x;
      const float* mcy = &my[it].x;
      #pragma unroll
      for (int j = 0; j < 4; ++j) {
        int bj = c4 - 1 + j;
        bool valid = rowv && ((unsigned)bj < (unsigned)TW);
        int ci = mr * SW + c4 + j;     // mag coords of center
        // X
        int rcx = (int)((rcpx[it] >> (8 * j)) & 255u);
        int ip = rcx & 7;
        int dr = (int)((DR_PACK >> (2 * ip)) & 3u) - 1;
        int dc = (int)((DC_PACK >> (2 * ip)) & 3u) - 1;
        int off = dr * SW + dc;
        float mcv = mcx[j];
        float n1 = rX[ci + off];
        float n2 = rX[ci - off];
        float thx = (fminf(mcv - n1, mcv - n2) > 0.f) ? mcv : 0.f;
        // Y
        int rcy = (int)((rcpy[it] >> (8 * j)) & 255u);
        ip = rcy & 7;
        dr = (int)((DR_PACK >> (2 * ip)) & 3u) - 1;
        dc = (int)((DC_PACK >> (2 * ip)) & 3u) - 1;
        off = dr * SW + dc;
        float mcw = mcy[j];
        float m1 = rY[ci + off];
        float m2 = rY[ci - off];
        float thy = (fminf(mcw - m1, mcw - m2) > 0.f) ? mcw : 0.f;
        // loss (masked)
        s += valid ? fabsf(thx - thy) : 0.f;
        so += valid ? abs(rcx - rcy) : 0;
      }
    }
  }
  return s + 45.f * (float)so;
}

__global__ void __launch_bounds__(NT)
canny_loss_kernel(const float* __restrict__ X, const float* __restrict__ Y,
                  float* __restrict__ out, Blur5 kb)
{
  __shared__ float reg[2 * HB_R * SW];          // 39168 B
  __shared__ float red[NT / 64];
  float* rX = reg;
  float* rY = reg + HB_R * SW;

  // grid: 1024 blocks = 16 batch x 8 row-tiles x 8 col-tiles (= 4 blocks/CU)
  const int idx = blockIdx.x;
  const int b  = idx >> 6;
  const int tr = (idx >> 3) & 7;
  const int tc = idx & 7;
  const int base_r = tr * TH;
  const int base_c = tc * TW;
  const float* xb = X + (size_t)b * HH * WW;
  const float* yb = Y + (size_t)b * HH * WW;

  const bool interior = (tr >= 1) & (tr <= 6) & (tc >= 1) & (tc <= 6);
  float s = interior
      ? canny_tile_loss<true >(xb, yb, base_r, base_c, rX, rY, kb)
      : canny_tile_loss<false>(xb, yb, base_r, base_c, rX, rY, kb);

  // wave reduce, cross-wave via LDS, one atomic per block
  #pragma unroll
  for (int off = 32; off >= 1; off >>= 1) s += __shfl_down(s, off, 64);
  const int tid = threadIdx.x;
  const int lane = tid & 63, wv = tid >> 6;
  if (lane == 0) red[wv] = s;
  __syncthreads();
  if (tid == 0) {
    float t = red[0] + red[1] + red[2] + red[3];
    atomicAdd(out, t * (1.0f / ((float)HH * (float)WW)));
  }
}

extern "C" void kernel_launch(void* const* d_in, const int* in_sizes, int n_in,
                              void* d_out, int out_size, void* d_ws, size_t ws_size,
                              hipStream_t stream)
{
  const float* X = (const float*)d_in[0];
  const float* Y = (const float*)d_in[1];
  float* out = (float*)d_out;

  hipMemsetAsync(out, 0, (size_t)out_size * sizeof(float), stream);

  // Gaussian 1D weights in double, cast to f32 (matches reference f64->f32 path)
  Blur5 kb;
  {
    double g[5], ssum = 0.0;
    for (int i = 0; i < 5; ++i) { double d = i - 2; g[i] = std::exp(-(d * d) / 2.0); ssum += g[i]; }
    for (int i = 0; i < 5; ++i) kb.w[i] = (float)(g[i] / ssum);
  }

  canny_loss_kernel<<<1024, NT, 0, stream>>>(X, Y, out, kb);
}